// Round 7
// baseline (114.061 us; speedup 1.0000x reference)
//
#include <hip/hip_runtime.h>
#include <math.h>

#define N 64
#define F 64
#define W 40
#define D 512
#define LSM 9.0f
#define LLSE 6.0f
#define MARG 0.2f

typedef _Float16 f16x8 __attribute__((ext_vector_type(8)));
typedef _Float16 f16x4 __attribute__((ext_vector_type(4)));
typedef float f32x4 __attribute__((ext_vector_type(4)));

// layouts (halves), linear:
//  img_h per i: [64][512]                      (32768)
//  cap_h per j: [48][512], rows 40..47 = 0     (24576)
//  G_h  per j: [48][64], zero outside 40x40   (3072)

// ---------------- k_pre: grid 320 ----------------
__global__ __launch_bounds__(256) void k_pre(
    const float* __restrict__ img, const float* __restrict__ cap,
    _Float16* __restrict__ img_h, _Float16* __restrict__ cap_h,
    _Float16* __restrict__ G_h, float* __restrict__ n1) {
  __shared__ __align__(16) _Float16 capT[4 * 48 * 128];  // 48 KB (cap blocks only)
  int t = threadIdx.x;
  int lane = t & 63;
  int b = blockIdx.x;
  if (b < 256) {
    int i = b >> 2;
    int f = ((b & 3) << 4) + (t >> 4);
    int q = t & 15;
    const float* row = img + ((size_t)i * F + f) * D + q * 32;
    _Float16* drow = img_h + ((size_t)i * F + f) * D + q * 32;
    float s = 0.f;
#pragma unroll
    for (int k = 0; k < 4; ++k) {
      float4 u = *(const float4*)(row + k * 8);
      float4 v = *(const float4*)(row + k * 8 + 4);
      s += u.x * u.x + u.y * u.y + u.z * u.z + u.w * u.w;
      s += v.x * v.x + v.y * v.y + v.z * v.z + v.w * v.w;
      f16x8 h;
      h[0] = (_Float16)u.x; h[1] = (_Float16)u.y; h[2] = (_Float16)u.z; h[3] = (_Float16)u.w;
      h[4] = (_Float16)v.x; h[5] = (_Float16)v.y; h[6] = (_Float16)v.z; h[7] = (_Float16)v.w;
      *(f16x8*)(drow + k * 8) = h;
    }
    s += __shfl_xor(s, 1);
    s += __shfl_xor(s, 2);
    s += __shfl_xor(s, 4);
    s += __shfl_xor(s, 8);
    if (q == 0) n1[i * F + f] = sqrtf(s);
  } else {
    int j = b - 256;
    int wv = t >> 6;
    const float* src = cap + (size_t)j * W * D;
    _Float16* dst = cap_h + (size_t)j * 24576;
#pragma unroll
    for (int k = 0; k < 12; ++k) {
      int slot = t + k * 256;  // 48 rows x 64 slots
      int w = slot >> 6, d = (slot & 63) * 8;
      float4 u = {0.f, 0.f, 0.f, 0.f}, v = {0.f, 0.f, 0.f, 0.f};
      if (w < W) {
        u = *(const float4*)(src + (size_t)w * D + d);
        v = *(const float4*)(src + (size_t)w * D + d + 4);
      }
      f16x8 h;
      h[0] = (_Float16)u.x; h[1] = (_Float16)u.y; h[2] = (_Float16)u.z; h[3] = (_Float16)u.w;
      h[4] = (_Float16)v.x; h[5] = (_Float16)v.y; h[6] = (_Float16)v.z; h[7] = (_Float16)v.w;
      int ch = d >> 7, din = d & 127;
      *(f16x8*)(dst + w * 512 + d) = h;  // linear global
      *(f16x8*)(capT + ch * 6144 + w * 128 + (din ^ ((w & 7) << 3))) = h;  // LDS swizzled
    }
    __syncthreads();
    int rlo = lane & 15, hi = lane >> 4;
    int koff = hi * 8, sw = (rlo & 7) << 3;
    _Float16* gb = G_h + (size_t)j * 3072;
    for (int tile = wv; tile < 9; tile += 4) {
      int mt = tile / 3, kt = tile % 3;
      f32x4 acc = (f32x4)0.f;
#pragma unroll
      for (int ks = 0; ks < 16; ++ks) {
        int kk = ks * 32 + koff;
        int ch = kk >> 7, din = (kk & 127) ^ sw;
        f16x8 af = *(const f16x8*)(capT + ch * 6144 + (mt * 16 + rlo) * 128 + din);
        f16x8 bf = *(const f16x8*)(capT + ch * 6144 + (kt * 16 + rlo) * 128 + din);
        acc = __builtin_amdgcn_mfma_f32_16x16x32_f16(af, bf, acc, 0, 0, 0);
      }
#pragma unroll
      for (int r = 0; r < 4; ++r) {
        int w = mt * 16 + hi * 4 + r, k = kt * 16 + rlo;
        float val = (w < W && k < W) ? acc[r] : 0.f;
        gb[w * 64 + k] = (_Float16)val;
      }
    }
    // zero G cols 48..63 (K-tail read by k_main against E=0 cols)
    for (int idx = t; idx < 96; idx += 256) {
      int w = idx >> 1, c8 = 48 + (idx & 1) * 8;
      *(f16x8*)(gb + w * 64 + c8) = (f16x8)(_Float16)0.f;
    }
  }
}

// ---------------- k_main: block = one (i,j) pair, 2 waves = 2 f-halves ----------------
// grid 4096 x 128thr. xcd = bid&7 -> (32i x 16j) tile per XCD: 2.8 MB L2-resident.
// Per wave: 48w x 32f A-tile (acc 24 regs), private Es 32x64 swizzled.
// Cross-wave coupling: rnorm exchange (48 floats) + final LSE combine. 2 barriers.
__global__ __launch_bounds__(128, 6) void k_main(
    const _Float16* __restrict__ img_h, const _Float16* __restrict__ cap_h,
    const int* __restrict__ imgL, const int* __restrict__ capL,
    const float* __restrict__ n1g, const _Float16* __restrict__ G_h,
    float* __restrict__ S) {
  __shared__ __align__(16) _Float16 Es[2][2048];  // 8 KB: [h][f_loc 32][64 cols swz]
  __shared__ float rnX[2][48];
  __shared__ float efX[2];

  int t = threadIdx.x;
  int lane = t & 63, h = t >> 6;  // h = f-half (frames h*32 .. h*32+31)
  int rlo = lane & 15, hi = lane >> 4;
  int koff = hi * 8;
  int sw = (rlo & 7) << 3;

  int bid = blockIdx.x;
  int xcd = bid & 7, s0 = bid >> 3;
  int i = (xcd >> 2) * 32 + (s0 & 31);
  int j = (xcd & 3) * 16 + (s0 >> 5);

  int iL = imgL[i], cL = capL[j];
  _Float16* Ew = &Es[h][0];

  // zero private Es slice (cols 48..63 stay zero = K-tail for P-phase)
#pragma unroll
  for (int k = 0; k < 4; ++k) ((f16x8*)Ew)[lane + k * 64] = (f16x8)(_Float16)0.f;

  float n1lane = n1g[i * F + h * 32 + (lane & 31)];

  // ---- A-phase: A[w][f] = cap_w . img_f, 48w x 32f tile (96 MFMA) ----
  const _Float16* cb = cap_h + (size_t)j * 24576 + rlo * 512 + koff;
  const _Float16* ib = img_h + (size_t)i * 32768 + (size_t)(h * 32 + rlo) * 512 + koff;
  f32x4 acc[3][2];
#pragma unroll
  for (int mt = 0; mt < 3; ++mt)
#pragma unroll
    for (int nt = 0; nt < 2; ++nt) acc[mt][nt] = (f32x4)0.f;

#pragma unroll
  for (int ks = 0; ks < 16; ++ks) {
    int kk = ks * 32;
    f16x8 af[3], bf[2];
#pragma unroll
    for (int mt = 0; mt < 3; ++mt) af[mt] = *(const f16x8*)(cb + mt * 8192 + kk);
#pragma unroll
    for (int nt = 0; nt < 2; ++nt) bf[nt] = *(const f16x8*)(ib + nt * 8192 + kk);
#pragma unroll
    for (int mt = 0; mt < 3; ++mt)
#pragma unroll
      for (int nt = 0; nt < 2; ++nt)
        acc[mt][nt] = __builtin_amdgcn_mfma_f32_16x16x32_f16(af[mt], bf[nt], acc[mt][nt], 0, 0, 0);
  }

  // ---- rnorm partials over this wave's 32 f (masked), exchange via LDS ----
#pragma unroll
  for (int mt = 0; mt < 3; ++mt)
#pragma unroll
    for (int r = 0; r < 4; ++r) {
      float s = 0.f;
#pragma unroll
      for (int nt = 0; nt < 2; ++nt) {
        float a = acc[mt][nt][r];
        float l = a > 0.f ? a : 0.1f * a;
        s += ((h * 32 + nt * 16 + rlo) < iL) ? l * l : 0.f;
      }
#pragma unroll
      for (int d = 1; d < 16; d <<= 1) s += __shfl_xor(s, d);
      if (rlo == 0) rnX[h][mt * 16 + hi * 4 + r] = s;
    }
  __syncthreads();  // BAR 1: rnX complete

  // ---- fused softmax (logits in [-9,9], no max pass) + sn + Es write ----
  float sn[2] = {0.f, 0.f};
#pragma unroll
  for (int mt = 0; mt < 3; ++mt) {
    f16x4 ev[2];
#pragma unroll
    for (int r = 0; r < 4; ++r) {
      int w = mt * 16 + hi * 4 + r;
      float rs = rnX[0][w] + rnX[1][w];
      float rinv = 1.f / (sqrtf(rs) + 1e-8f);
#pragma unroll
      for (int nt = 0; nt < 2; ++nt) {
        float a = acc[mt][nt][r];
        float l = a > 0.f ? a : 0.1f * a;
        float e = (w < cL) ? __expf(LSM * l * rinv) : 0.f;
        sn[nt] = fmaf(e, a, sn[nt]);
        ev[nt][r] = (_Float16)e;
      }
    }
#pragma unroll
    for (int nt = 0; nt < 2; ++nt)
      *(f16x4*)(Ew + (nt * 16 + rlo) * 64 + ((mt * 16 + hi * 4) ^ sw)) = ev[nt];
  }
#pragma unroll
  for (int nt = 0; nt < 2; ++nt) {
    sn[nt] += __shfl_xor(sn[nt], 16);
    sn[nt] += __shfl_xor(sn[nt], 32);
  }

  // ---- P = E*G (12 MFMA, K=64 w/ zero tail; G symmetric) ----
  f32x4 P[2][3];
#pragma unroll
  for (int mtl = 0; mtl < 2; ++mtl)
#pragma unroll
    for (int ntl = 0; ntl < 3; ++ntl) P[mtl][ntl] = (f32x4)0.f;
#pragma unroll
  for (int ks2 = 0; ks2 < 2; ++ks2) {
    int kk2 = ks2 * 32 + koff;
    f16x8 bfg[3];
#pragma unroll
    for (int ntl = 0; ntl < 3; ++ntl)
      bfg[ntl] = *(const f16x8*)(G_h + (size_t)j * 3072 + (ntl * 16 + rlo) * 64 + kk2);
#pragma unroll
    for (int mtl = 0; mtl < 2; ++mtl) {
      f16x8 af = *(const f16x8*)(Ew + (mtl * 16 + rlo) * 64 + (kk2 ^ sw));
#pragma unroll
      for (int ntl = 0; ntl < 3; ++ntl)
        P[mtl][ntl] = __builtin_amdgcn_mfma_f32_16x16x32_f16(af, bfg[ntl], P[mtl][ntl], 0, 0, 0);
    }
  }

  // ---- n2^2 per f; sim; LSE over this wave's 32 f ----
  float ef = 0.f;
#pragma unroll
  for (int mtl = 0; mtl < 2; ++mtl) {
#pragma unroll
    for (int rr = 0; rr < 4; ++rr) {
      int fl = mtl * 16 + hi * 4 + rr;
      int fsw2 = (fl & 7) << 3;
      float n2s = 0.f;
#pragma unroll
      for (int ntl = 0; ntl < 3; ++ntl) {
        float evv = (float)Ew[fl * 64 + ((ntl * 16 + rlo) ^ fsw2)];
        n2s = fmaf(P[mtl][ntl][rr], evv, n2s);
      }
#pragma unroll
      for (int d = 1; d < 16; d <<= 1) n2s += __shfl_xor(n2s, d);
      float nm = __shfl(sn[mtl], hi * 4 + rr);
      float n1v = __shfl(n1lane, fl);
      float denom = n1v * sqrtf(fmaxf(n2s, 0.f));
      float sim = nm / fmaxf(denom, 1e-20f);
      ef += ((h * 32 + fl) < iL) ? __expf(LLSE * sim) : 0.f;
    }
  }
  ef += __shfl_xor(ef, 16);
  ef += __shfl_xor(ef, 32);
  if (lane == 0) efX[h] = ef;
  __syncthreads();  // BAR 2: both halves' LSE partials
  if (t == 0) S[(j << 6) + i] = __logf(efX[0] + efX[1]) * (1.f / LLSE);
}

// ---------------- k_loss ----------------
__global__ void k_loss(const float* __restrict__ S, float* __restrict__ out) {
  __shared__ float red[128];
  int t = threadIdx.x;
  float m = -1e30f;
  if (t < 64) {
    int a = t;
    float da = S[a * N + a];
    for (int b = 0; b < N; ++b)
      if (b != a) m = fmaxf(m, MARG + S[a * N + b] - da);
  } else {
    int b = t - 64;
    float db = S[b * N + b];
    for (int a = 0; a < N; ++a)
      if (a != b) m = fmaxf(m, MARG + S[a * N + b] - db);
  }
  m = fmaxf(m, 0.f);
  red[t] = m;
  __syncthreads();
  if (t == 0) {
    float s = 0.f;
    for (int k = 0; k < 128; ++k) s += red[k];
    *out = s;
  }
}

extern "C" void kernel_launch(void* const* d_in, const int* in_sizes, int n_in,
                              void* d_out, int out_size, void* d_ws, size_t ws_size,
                              hipStream_t stream) {
  const float* img = (const float*)d_in[0];
  const float* cap = (const float*)d_in[1];
  const int* imgL = (const int*)d_in[2];
  const int* capL = (const int*)d_in[3];

  char* wsb = (char*)d_ws;
  float* n1 = (float*)wsb;                                // 16 KB
  float* S = (float*)(wsb + 16384);                       // 16 KB
  _Float16* img_h = (_Float16*)(wsb + 32768);             // 4 MB
  _Float16* cap_h = (_Float16*)(wsb + 32768 + 4194304);   // 3 MB
  _Float16* G_h = (_Float16*)(wsb + 32768 + 4194304 + 3145728);  // 384 KB

  k_pre<<<320, 256, 0, stream>>>(img, cap, img_h, cap_h, G_h, n1);
  k_main<<<4096, 128, 0, stream>>>(img_h, cap_h, imgL, capL, n1, G_h, S);
  k_loss<<<1, 128, 0, stream>>>(S, (float*)d_out);
}

// Round 8
// 59.606 us; speedup vs baseline: 1.9136x; 1.9136x over previous
//
#include <hip/hip_runtime.h>
#include <math.h>

#define N 64
#define F 64
#define W 40
#define D 512
#define LSM 9.0f
#define LLSE 6.0f
#define MARG 0.2f
#define ESTR 56  // Es row stride in halves

typedef _Float16 f16x8 __attribute__((ext_vector_type(8)));
typedef _Float16 f16x4 __attribute__((ext_vector_type(4)));
typedef float f32x4 __attribute__((ext_vector_type(4)));

__device__ inline void gll16(const void* g, void* l) {
  __builtin_amdgcn_global_load_lds(
      (const __attribute__((address_space(1))) unsigned int*)g,
      (__attribute__((address_space(3))) unsigned int*)l, 16, 0, 0);
}

// layouts (halves), K-chunked (8 chunks of 64) + XOR swizzle baked in:
//  img_h per i: [ch8][f64][64],  halfidx ^ ((f&7)<<3)              (32768)
//  cap_h per j: [ch8][w48][64], halfidx ^ ((w&7)<<3), rows 40..47=0 (24576)
//  G_h  per j: [w48][64] linear, zero outside 40x40                 (3072)

// ---------------- k_pre: grid 320 ----------------
__global__ __launch_bounds__(256) void k_pre(
    const float* __restrict__ img, const float* __restrict__ cap,
    _Float16* __restrict__ img_h, _Float16* __restrict__ cap_h,
    _Float16* __restrict__ G_h, float* __restrict__ n1) {
  __shared__ __align__(16) _Float16 capT[4 * 48 * 128];  // 48 KB (cap blocks only)
  int t = threadIdx.x;
  int lane = t & 63;
  int b = blockIdx.x;
  if (b < 256) {
    int i = b >> 2;
    int f = ((b & 3) << 4) + (t >> 4);
    int q = t & 15;
    const float* row = img + ((size_t)i * F + f) * D + q * 32;
    _Float16* dsti = img_h + (size_t)i * 32768;
    int fsw = (f & 7) << 3;
    float s = 0.f;
#pragma unroll
    for (int k = 0; k < 4; ++k) {
      float4 u = *(const float4*)(row + k * 8);
      float4 v = *(const float4*)(row + k * 8 + 4);
      s += u.x * u.x + u.y * u.y + u.z * u.z + u.w * u.w;
      s += v.x * v.x + v.y * v.y + v.z * v.z + v.w * v.w;
      f16x8 h;
      h[0] = (_Float16)u.x; h[1] = (_Float16)u.y; h[2] = (_Float16)u.z; h[3] = (_Float16)u.w;
      h[4] = (_Float16)v.x; h[5] = (_Float16)v.y; h[6] = (_Float16)v.z; h[7] = (_Float16)v.w;
      int d = q * 32 + k * 8;
      int ch = d >> 6, din = d & 63;
      *(f16x8*)(dsti + ch * 4096 + f * 64 + (din ^ fsw)) = h;
    }
    s += __shfl_xor(s, 1);
    s += __shfl_xor(s, 2);
    s += __shfl_xor(s, 4);
    s += __shfl_xor(s, 8);
    if (q == 0) n1[i * F + f] = sqrtf(s);
  } else {
    int j = b - 256;
    int wv = t >> 6;
    const float* src = cap + (size_t)j * W * D;
    _Float16* dst = cap_h + (size_t)j * 24576;
#pragma unroll
    for (int k = 0; k < 12; ++k) {
      int slot = t + k * 256;  // 48 rows x 64 col-chunks
      int w = slot >> 6, d = (slot & 63) * 8;
      float4 u = {0.f, 0.f, 0.f, 0.f}, v = {0.f, 0.f, 0.f, 0.f};
      if (w < W) {
        u = *(const float4*)(src + (size_t)w * D + d);
        v = *(const float4*)(src + (size_t)w * D + d + 4);
      }
      f16x8 h;
      h[0] = (_Float16)u.x; h[1] = (_Float16)u.y; h[2] = (_Float16)u.z; h[3] = (_Float16)u.w;
      h[4] = (_Float16)v.x; h[5] = (_Float16)v.y; h[6] = (_Float16)v.z; h[7] = (_Float16)v.w;
      int wsw = (w & 7) << 3;
      int ch2 = d >> 6, din2 = d & 63;
      *(f16x8*)(dst + ch2 * 3072 + w * 64 + (din2 ^ wsw)) = h;  // new global layout
      int chO = d >> 7, dinO = d & 127;
      *(f16x8*)(capT + chO * 6144 + w * 128 + (dinO ^ wsw)) = h;  // local for Gram
    }
    __syncthreads();
    int rlo = lane & 15, hi = lane >> 4;
    int koff = hi * 8, sw = (rlo & 7) << 3;
    _Float16* gb = G_h + (size_t)j * 3072;
    for (int tile = wv; tile < 9; tile += 4) {
      int mt = tile / 3, kt = tile % 3;
      f32x4 acc = (f32x4)0.f;
#pragma unroll
      for (int ks = 0; ks < 16; ++ks) {
        int kk = ks * 32 + koff;
        int ch = kk >> 7, din = (kk & 127) ^ sw;
        f16x8 af = *(const f16x8*)(capT + ch * 6144 + (mt * 16 + rlo) * 128 + din);
        f16x8 bf = *(const f16x8*)(capT + ch * 6144 + (kt * 16 + rlo) * 128 + din);
        acc = __builtin_amdgcn_mfma_f32_16x16x32_f16(af, bf, acc, 0, 0, 0);
      }
#pragma unroll
      for (int r = 0; r < 4; ++r) {
        int w = mt * 16 + hi * 4 + r, k = kt * 16 + rlo;
        float val = (w < W && k < W) ? acc[r] : 0.f;
        gb[w * 64 + k] = (_Float16)val;
      }
    }
    // zero G cols 48..63 (K-tail read by k_main against E garbage -> must be 0)
    for (int idx = t; idx < 96; idx += 256) {
      int w = idx >> 1, c8 = 48 + (idx & 1) * 8;
      *(f16x8*)(gb + w * 64 + c8) = (f16x8)(_Float16)0.f;
    }
  }
}

// stage one K-chunk (40 KB = 4 caps x 6KB + 2 imgs x 8KB) via global_load_lds
__device__ inline void stage_chunk(const char* capb, const char* imgb, int ch,
                                   char* dst, int wv, int lane) {
#pragma unroll
  for (int s = 0; s < 5; ++s) {
    int m = s * 8 + wv;  // wave-uniform segment id, 40 x 1KB segments
    const char* src;
    if (m < 24) {
      src = capb + (m / 6) * 49152 + ch * 6144 + (m % 6) * 1024;
    } else {
      int e = (m - 24) >> 3;
      src = imgb + e * 65536 + ch * 8192 + ((m - 24) & 7) * 1024;
    }
    gll16(src + lane * 16, dst + m * 1024);
  }
}

// ---------------- k_main: 512 blocks x 512 thr; block = 4j x 2i = 8 pairs ----------------
// wave = one (i,j) pair (zero-barrier epilogue). K-chunked dbuf LDS staging shared
// by all 8 waves; Es aliases the staging buffer after the last chunk.
__global__ __launch_bounds__(512, 4) void k_main(
    const _Float16* __restrict__ img_h, const _Float16* __restrict__ cap_h,
    const int* __restrict__ imgL, const int* __restrict__ capL,
    const float* __restrict__ n1g, const _Float16* __restrict__ G_h,
    float* __restrict__ S) {
  __shared__ __align__(16) char buf[81920];  // 2 x 40KB chunk dbuf; Es aliased later

  int t = threadIdx.x;
  int lane = t & 63, wv = t >> 6;
  int rlo = lane & 15, hi = lane >> 4;
  int koff = hi * 8;
  int sw = (rlo & 7) << 3;

  int bid = blockIdx.x;
  int xcd = bid & 7, s0 = bid >> 3;
  int it = xcd * 4 + (s0 >> 4);  // i-tile in [0,32): 8 imgs per XCD -> L2-hot
  int jt = s0 & 15;              // j-tile in [0,16)
  int jloc = wv & 3, iloc = wv >> 2;
  int j = jt * 4 + jloc;
  int i = it * 2 + iloc;
  int iL = imgL[i], cL = capL[j];

  const char* capb = (const char*)cap_h + (size_t)jt * 4 * 49152;
  const char* imgb = (const char*)img_h + (size_t)it * 2 * 65536;

  float n1lane = n1g[i * F + lane];

  f32x4 acc[3][4];
#pragma unroll
  for (int mt = 0; mt < 3; ++mt)
#pragma unroll
    for (int nt = 0; nt < 4; ++nt) acc[mt][nt] = (f32x4)0.f;

  // prologue: stage chunk 0
  stage_chunk(capb, imgb, 0, buf, wv, lane);
  __syncthreads();

  // ---- A-phase: 8 chunks, stage(c+1) || compute(c), 1 barrier/chunk ----
#pragma unroll
  for (int c = 0; c < 8; ++c) {
    char* cb = buf + (c & 1) * 40960;
    if (c < 7) stage_chunk(capb, imgb, c + 1, buf + ((c + 1) & 1) * 40960, wv, lane);
    const _Float16* myCap = (const _Float16*)cb + jloc * 3072;
    const _Float16* myImg = (const _Float16*)(cb + 24576) + iloc * 4096;
#pragma unroll
    for (int ks = 0; ks < 2; ++ks) {
      int col = (ks * 32 + koff) ^ sw;
      f16x8 af[3], bf[4];
#pragma unroll
      for (int mt = 0; mt < 3; ++mt) af[mt] = *(const f16x8*)(myCap + (mt * 16 + rlo) * 64 + col);
#pragma unroll
      for (int nt = 0; nt < 4; ++nt) bf[nt] = *(const f16x8*)(myImg + (nt * 16 + rlo) * 64 + col);
#pragma unroll
      for (int mt = 0; mt < 3; ++mt)
#pragma unroll
        for (int nt = 0; nt < 4; ++nt)
          acc[mt][nt] = __builtin_amdgcn_mfma_f32_16x16x32_f16(af[mt], bf[nt], acc[mt][nt], 0, 0, 0);
    }
    __syncthreads();  // staging reads done + next chunk's gll drained
  }

  // ---- epilogue: wave-private, zero barriers. Es aliases staging buffer ----
  _Float16* Ew = (_Float16*)(buf + wv * 7168);  // [64][ESTR=56] halves

  // rnorm: rinv per w from sum_f leaky(A)^2 (f-masked)
  float rinv[3][4];
#pragma unroll
  for (int mt = 0; mt < 3; ++mt)
#pragma unroll
    for (int r = 0; r < 4; ++r) {
      float s = 0.f;
#pragma unroll
      for (int nt = 0; nt < 4; ++nt) {
        float a = acc[mt][nt][r];
        float l = a > 0.f ? a : 0.1f * a;
        s += ((nt * 16 + rlo) < iL) ? l * l : 0.f;
      }
#pragma unroll
      for (int d = 1; d < 16; d <<= 1) s += __shfl_xor(s, d);
      rinv[mt][r] = 1.f / (sqrtf(s) + 1e-8f);
    }

  // fused softmax (logits in [-9,9] -> no max pass) + sn + Es write
  float sn[4] = {0.f, 0.f, 0.f, 0.f};
#pragma unroll
  for (int mt = 0; mt < 3; ++mt)
#pragma unroll
    for (int nt = 0; nt < 4; ++nt) {
      f16x4 ev;
#pragma unroll
      for (int r = 0; r < 4; ++r) {
        int w = mt * 16 + hi * 4 + r;
        float a = acc[mt][nt][r];
        float l = a > 0.f ? a : 0.1f * a;
        float e = (w < cL) ? __expf(LSM * l * rinv[mt][r]) : 0.f;
        sn[nt] = fmaf(e, a, sn[nt]);
        ev[r] = (_Float16)e;
      }
      *(f16x4*)(Ew + (nt * 16 + rlo) * ESTR + mt * 16 + hi * 4) = ev;
    }
#pragma unroll
  for (int nt = 0; nt < 4; ++nt) {
    sn[nt] += __shfl_xor(sn[nt], 16);
    sn[nt] += __shfl_xor(sn[nt], 32);
  }

  // P = E*G (24 MFMA; K-tail cols >=48 killed by G zero-cols)
  const _Float16* gB = G_h + (size_t)j * 3072 + rlo * 64 + koff;
  f32x4 P[4][3];
#pragma unroll
  for (int mtl = 0; mtl < 4; ++mtl)
#pragma unroll
    for (int ntl = 0; ntl < 3; ++ntl) P[mtl][ntl] = (f32x4)0.f;
#pragma unroll
  for (int ks2 = 0; ks2 < 2; ++ks2) {
    int kk2 = ks2 * 32;
    f16x8 bfg[3];
#pragma unroll
    for (int ntl = 0; ntl < 3; ++ntl) bfg[ntl] = *(const f16x8*)(gB + ntl * 1024 + kk2);
#pragma unroll
    for (int mtl = 0; mtl < 4; ++mtl) {
      f16x8 af = *(const f16x8*)(Ew + (mtl * 16 + rlo) * ESTR + kk2 + koff);
#pragma unroll
      for (int ntl = 0; ntl < 3; ++ntl)
        P[mtl][ntl] = __builtin_amdgcn_mfma_f32_16x16x32_f16(af, bfg[ntl], P[mtl][ntl], 0, 0, 0);
    }
  }

  // n2^2 per f; sim; LSE over f; one store per wave
  float ef = 0.f;
#pragma unroll
  for (int mtl = 0; mtl < 4; ++mtl) {
#pragma unroll
    for (int rr = 0; rr < 4; ++rr) {
      int fm = mtl * 16 + hi * 4 + rr;
      float n2s = 0.f;
#pragma unroll
      for (int ntl = 0; ntl < 3; ++ntl) {
        float evv = (float)Ew[fm * ESTR + ntl * 16 + rlo];
        n2s = fmaf(P[mtl][ntl][rr], evv, n2s);
      }
#pragma unroll
      for (int d = 1; d < 16; d <<= 1) n2s += __shfl_xor(n2s, d);
      float nm = __shfl(sn[mtl], hi * 4 + rr);
      float n1v = __shfl(n1lane, fm);
      float denom = n1v * sqrtf(fmaxf(n2s, 0.f));
      float sim = nm / fmaxf(denom, 1e-20f);
      ef += (fm < iL) ? __expf(LLSE * sim) : 0.f;
    }
  }
  ef += __shfl_xor(ef, 16);
  ef += __shfl_xor(ef, 32);
  if (lane == 0) S[(j << 6) + i] = __logf(ef) * (1.f / LLSE);
}

// ---------------- k_loss ----------------
__global__ void k_loss(const float* __restrict__ S, float* __restrict__ out) {
  __shared__ float red[128];
  int t = threadIdx.x;
  float m = -1e30f;
  if (t < 64) {
    int a = t;
    float da = S[a * N + a];
    for (int b = 0; b < N; ++b)
      if (b != a) m = fmaxf(m, MARG + S[a * N + b] - da);
  } else {
    int b = t - 64;
    float db = S[b * N + b];
    for (int a = 0; a < N; ++a)
      if (a != b) m = fmaxf(m, MARG + S[a * N + b] - db);
  }
  m = fmaxf(m, 0.f);
  red[t] = m;
  __syncthreads();
  if (t == 0) {
    float s = 0.f;
    for (int k = 0; k < 128; ++k) s += red[k];
    *out = s;
  }
}

extern "C" void kernel_launch(void* const* d_in, const int* in_sizes, int n_in,
                              void* d_out, int out_size, void* d_ws, size_t ws_size,
                              hipStream_t stream) {
  const float* img = (const float*)d_in[0];
  const float* cap = (const float*)d_in[1];
  const int* imgL = (const int*)d_in[2];
  const int* capL = (const int*)d_in[3];

  char* wsb = (char*)d_ws;
  float* n1 = (float*)wsb;                                // 16 KB
  float* S = (float*)(wsb + 16384);                       // 16 KB
  _Float16* img_h = (_Float16*)(wsb + 32768);             // 4 MB
  _Float16* cap_h = (_Float16*)(wsb + 32768 + 4194304);   // 3 MB
  _Float16* G_h = (_Float16*)(wsb + 32768 + 4194304 + 3145728);  // 384 KB

  k_pre<<<320, 256, 0, stream>>>(img, cap, img_h, cap_h, G_h, n1);
  k_main<<<512, 512, 0, stream>>>(img_h, cap_h, imgL, capL, n1, G_h, S);
  k_loss<<<1, 128, 0, stream>>>(S, (float*)d_out);
}

// Round 9
// 56.809 us; speedup vs baseline: 2.0078x; 1.0492x over previous
//
#include <hip/hip_runtime.h>
#include <math.h>

#define N 64
#define F 64
#define W 40
#define D 512
#define LSM 9.0f
#define LLSE 6.0f
#define MARG 0.2f
#define ESTR 56  // Es row stride in halves

typedef _Float16 f16x8 __attribute__((ext_vector_type(8)));
typedef _Float16 f16x4 __attribute__((ext_vector_type(4)));
typedef float f32x4 __attribute__((ext_vector_type(4)));

__device__ inline void gll16(const void* g, void* l) {
  __builtin_amdgcn_global_load_lds(
      (const __attribute__((address_space(1))) unsigned int*)g,
      (__attribute__((address_space(3))) unsigned int*)l, 16, 0, 0);
}

// layouts (halves), K-chunked (8 chunks of 64) + XOR swizzle baked in:
//  img_h per i: [ch8][f64][64],  halfidx ^ ((f&7)<<3)               (32768)
//  cap_h per j: [ch8][w48][64], halfidx ^ ((w&7)<<3), rows 40..47=0 (24576)
//  G_h  per j: [w48][64] linear, zero outside 40 rows/48 cols       (3072)

// ---------------- k_pre: grid 192 x 512 ----------------
// blocks [0,128): img convert fp16 swizzled-chunked + n1 (32 rows/block)
// blocks [128,192): cap convert + Gram via MFMA (8 waves)
__global__ __launch_bounds__(512) void k_pre(
    const float* __restrict__ img, const float* __restrict__ cap,
    _Float16* __restrict__ img_h, _Float16* __restrict__ cap_h,
    _Float16* __restrict__ G_h, float* __restrict__ n1) {
  __shared__ __align__(16) _Float16 capT[4 * 48 * 128];  // 48 KB (cap blocks only)
  int t = threadIdx.x;
  int b = blockIdx.x;
  if (b < 128) {
    int i = b >> 1;
    int f = ((b & 1) << 5) + (t >> 4);
    int q = t & 15;
    const float* row = img + ((size_t)i * F + f) * D + q * 32;
    _Float16* dsti = img_h + (size_t)i * 32768;
    int fsw = (f & 7) << 3;
    float s = 0.f;
#pragma unroll
    for (int k = 0; k < 4; ++k) {
      float4 u = *(const float4*)(row + k * 8);
      float4 v = *(const float4*)(row + k * 8 + 4);
      s += u.x * u.x + u.y * u.y + u.z * u.z + u.w * u.w;
      s += v.x * v.x + v.y * v.y + v.z * v.z + v.w * v.w;
      f16x8 h;
      h[0] = (_Float16)u.x; h[1] = (_Float16)u.y; h[2] = (_Float16)u.z; h[3] = (_Float16)u.w;
      h[4] = (_Float16)v.x; h[5] = (_Float16)v.y; h[6] = (_Float16)v.z; h[7] = (_Float16)v.w;
      int d = q * 32 + k * 8;
      int ch = d >> 6, din = d & 63;
      *(f16x8*)(dsti + ch * 4096 + f * 64 + (din ^ fsw)) = h;
    }
    s += __shfl_xor(s, 1);
    s += __shfl_xor(s, 2);
    s += __shfl_xor(s, 4);
    s += __shfl_xor(s, 8);
    if (q == 0) n1[i * F + f] = sqrtf(s);
  } else {
    int j = b - 128;
    int lane = t & 63, wv = t >> 6;
    const float* src = cap + (size_t)j * W * D;
    _Float16* dst = cap_h + (size_t)j * 24576;
#pragma unroll
    for (int k = 0; k < 6; ++k) {
      int slot = t + k * 512;  // 48 rows x 64 col-chunks
      int w = slot >> 6, d = (slot & 63) * 8;
      float4 u = {0.f, 0.f, 0.f, 0.f}, v = {0.f, 0.f, 0.f, 0.f};
      if (w < W) {
        u = *(const float4*)(src + (size_t)w * D + d);
        v = *(const float4*)(src + (size_t)w * D + d + 4);
      }
      f16x8 h;
      h[0] = (_Float16)u.x; h[1] = (_Float16)u.y; h[2] = (_Float16)u.z; h[3] = (_Float16)u.w;
      h[4] = (_Float16)v.x; h[5] = (_Float16)v.y; h[6] = (_Float16)v.z; h[7] = (_Float16)v.w;
      int wsw = (w & 7) << 3;
      int ch2 = d >> 6, din2 = d & 63;
      *(f16x8*)(dst + ch2 * 3072 + w * 64 + (din2 ^ wsw)) = h;
      int chO = d >> 7, dinO = d & 127;
      *(f16x8*)(capT + chO * 6144 + w * 128 + (dinO ^ wsw)) = h;
    }
    __syncthreads();
    int rlo = lane & 15, hi = lane >> 4;
    int koff = hi * 8, sw = (rlo & 7) << 3;
    _Float16* gb = G_h + (size_t)j * 3072;
    for (int tile = wv; tile < 9; tile += 8) {
      int mt = tile / 3, kt = tile % 3;
      f32x4 acc = (f32x4)0.f;
#pragma unroll
      for (int ks = 0; ks < 16; ++ks) {
        int kk = ks * 32 + koff;
        int ch = kk >> 7, din = (kk & 127) ^ sw;
        f16x8 af = *(const f16x8*)(capT + ch * 6144 + (mt * 16 + rlo) * 128 + din);
        f16x8 bf = *(const f16x8*)(capT + ch * 6144 + (kt * 16 + rlo) * 128 + din);
        acc = __builtin_amdgcn_mfma_f32_16x16x32_f16(af, bf, acc, 0, 0, 0);
      }
#pragma unroll
      for (int r = 0; r < 4; ++r) {
        int w = mt * 16 + hi * 4 + r, k = kt * 16 + rlo;
        float val = (w < W && k < W) ? acc[r] : 0.f;
        gb[w * 64 + k] = (_Float16)val;
      }
    }
    // zero G cols 48..63 (K-tail read by k_main against E garbage -> must be 0)
    if (t < 96) {
      int w = t >> 1, c8 = 48 + (t & 1) * 8;
      *(f16x8*)(gb + w * 64 + c8) = (f16x8)(_Float16)0.f;
    }
  }
}

// stage one K-chunk (40 KB = 4 caps x 6KB + 2 imgs x 8KB): 5 gll16 per wave
__device__ inline void stage_chunk(const char* capb, const char* imgb, int ch,
                                   char* dst, int wv, int lane) {
#pragma unroll
  for (int s = 0; s < 5; ++s) {
    int m = s * 8 + wv;  // wave-uniform segment id, 40 x 1KB segments
    const char* src;
    if (m < 24) {
      src = capb + (m / 6) * 49152 + ch * 6144 + (m % 6) * 1024;
    } else {
      int e = (m - 24) >> 3;
      src = imgb + e * 65536 + ch * 8192 + ((m - 24) & 7) * 1024;
    }
    gll16(src + lane * 16, dst + m * 1024);
  }
}

// ---------------- k_main: 512 blocks x 512 thr; block = 4j x 2i = 8 pairs ----------------
// Counted-vmcnt pipeline (T3/T4): stage(c+1) stays in flight across both barriers;
// vmcnt never drained to 0 inside the loop. Wave = one pair; epilogue barrier-free.
__global__ __launch_bounds__(512, 4) void k_main(
    const _Float16* __restrict__ img_h, const _Float16* __restrict__ cap_h,
    const int* __restrict__ imgL, const int* __restrict__ capL,
    const float* __restrict__ n1g, const _Float16* __restrict__ G_h,
    float* __restrict__ S) {
  __shared__ __align__(16) char buf[81920];  // 2 x 40KB chunk dbuf; Es aliased later

  int t = threadIdx.x;
  int lane = t & 63, wv = t >> 6;
  int rlo = lane & 15, hi = lane >> 4;
  int koff = hi * 8;
  int sw = (rlo & 7) << 3;

  int bid = blockIdx.x;
  int xcd = bid & 7, s0 = bid >> 3;
  int it = xcd * 4 + (s0 >> 4);  // i-tile in [0,32): 8 imgs per XCD -> L2-hot
  int jt = s0 & 15;              // j-tile in [0,16)
  int jloc = wv & 3, iloc = wv >> 2;
  int j = jt * 4 + jloc;
  int i = it * 2 + iloc;

  // issue BEFORE stage(0): these are the oldest vmcnt entries
  int iL = imgL[i], cL = capL[j];

  const char* capb = (const char*)cap_h + (size_t)jt * 4 * 49152;
  const char* imgb = (const char*)img_h + (size_t)it * 2 * 65536;

  f32x4 acc[3][4];
#pragma unroll
  for (int mt = 0; mt < 3; ++mt)
#pragma unroll
    for (int nt = 0; nt < 4; ++nt) acc[mt][nt] = (f32x4)0.f;

  // prologue: stage chunk 0 (5 gll in flight)
  stage_chunk(capb, imgb, 0, buf, wv, lane);

  // ---- A-phase: counted-vmcnt two-barrier pipeline, 8 chunks ----
#pragma unroll
  for (int c = 0; c < 8; ++c) {
    if (c < 7) stage_chunk(capb, imgb, c + 1, buf + ((c + 1) & 1) * 40960, wv, lane);
    if (c < 7) {
      asm volatile("s_waitcnt vmcnt(5)" ::: "memory");  // chunk-c loads done; c+1 in flight
    } else {
      asm volatile("s_waitcnt vmcnt(0)" ::: "memory");
    }
    __builtin_amdgcn_s_barrier();          // all waves' chunk-c data landed
    __builtin_amdgcn_sched_barrier(0);
    const char* cb = buf + (c & 1) * 40960;
    const _Float16* myCap = (const _Float16*)cb + jloc * 3072;
    const _Float16* myImg = (const _Float16*)(cb + 24576) + iloc * 4096;
#pragma unroll
    for (int ks = 0; ks < 2; ++ks) {
      int col = (ks * 32 + koff) ^ sw;
      f16x8 af[3], bf[4];
#pragma unroll
      for (int mt = 0; mt < 3; ++mt) af[mt] = *(const f16x8*)(myCap + (mt * 16 + rlo) * 64 + col);
#pragma unroll
      for (int nt = 0; nt < 4; ++nt) bf[nt] = *(const f16x8*)(myImg + (nt * 16 + rlo) * 64 + col);
#pragma unroll
      for (int mt = 0; mt < 3; ++mt)
#pragma unroll
        for (int nt = 0; nt < 4; ++nt)
          acc[mt][nt] = __builtin_amdgcn_mfma_f32_16x16x32_f16(af[mt], bf[nt], acc[mt][nt], 0, 0, 0);
    }
    __builtin_amdgcn_sched_barrier(0);
    __builtin_amdgcn_s_barrier();          // all reads of buf[c&1] done -> c+2 may overwrite
  }

  // ---- epilogue: wave-private, zero barriers. Es aliases staging buffer ----
  _Float16* Ew = (_Float16*)(buf + wv * 7168);  // [64][ESTR=56] halves
  float n1lane = n1g[i * F + lane];

  // rnorm: rinv per w from sum_f leaky(A)^2 (f-masked)
  float rinv[3][4];
#pragma unroll
  for (int mt = 0; mt < 3; ++mt)
#pragma unroll
    for (int r = 0; r < 4; ++r) {
      float s = 0.f;
#pragma unroll
      for (int nt = 0; nt < 4; ++nt) {
        float a = acc[mt][nt][r];
        float l = a > 0.f ? a : 0.1f * a;
        s += ((nt * 16 + rlo) < iL) ? l * l : 0.f;
      }
#pragma unroll
      for (int d = 1; d < 16; d <<= 1) s += __shfl_xor(s, d);
      rinv[mt][r] = 1.f / (sqrtf(s) + 1e-8f);
    }

  // fused softmax (logits in [-9,9] -> no max pass) + sn + Es write
  float sn[4] = {0.f, 0.f, 0.f, 0.f};
#pragma unroll
  for (int mt = 0; mt < 3; ++mt)
#pragma unroll
    for (int nt = 0; nt < 4; ++nt) {
      f16x4 ev;
#pragma unroll
      for (int r = 0; r < 4; ++r) {
        int w = mt * 16 + hi * 4 + r;
        float a = acc[mt][nt][r];
        float l = a > 0.f ? a : 0.1f * a;
        float e = (w < cL) ? __expf(LSM * l * rinv[mt][r]) : 0.f;
        sn[nt] = fmaf(e, a, sn[nt]);
        ev[r] = (_Float16)e;
      }
      *(f16x4*)(Ew + (nt * 16 + rlo) * ESTR + mt * 16 + hi * 4) = ev;
    }
#pragma unroll
  for (int nt = 0; nt < 4; ++nt) {
    sn[nt] += __shfl_xor(sn[nt], 16);
    sn[nt] += __shfl_xor(sn[nt], 32);
  }

  // P = E*G (24 MFMA; E K-tail garbage cols >=48 killed by G zero-cols; G symmetric)
  const _Float16* gB = G_h + (size_t)j * 3072 + rlo * 64 + koff;
  f32x4 P[4][3];
#pragma unroll
  for (int mtl = 0; mtl < 4; ++mtl)
#pragma unroll
    for (int ntl = 0; ntl < 3; ++ntl) P[mtl][ntl] = (f32x4)0.f;
#pragma unroll
  for (int ks2 = 0; ks2 < 2; ++ks2) {
    int kk2 = ks2 * 32;
    f16x8 bfg[3];
#pragma unroll
    for (int ntl = 0; ntl < 3; ++ntl) bfg[ntl] = *(const f16x8*)(gB + ntl * 1024 + kk2);
#pragma unroll
    for (int mtl = 0; mtl < 4; ++mtl) {
      f16x8 af = *(const f16x8*)(Ew + (mtl * 16 + rlo) * ESTR + kk2 + koff);
#pragma unroll
      for (int ntl = 0; ntl < 3; ++ntl)
        P[mtl][ntl] = __builtin_amdgcn_mfma_f32_16x16x32_f16(af, bfg[ntl], P[mtl][ntl], 0, 0, 0);
    }
  }

  // n2^2 per f; sim; LSE over f; one store per wave
  float ef = 0.f;
#pragma unroll
  for (int mtl = 0; mtl < 4; ++mtl) {
#pragma unroll
    for (int rr = 0; rr < 4; ++rr) {
      int fm = mtl * 16 + hi * 4 + rr;
      float n2s = 0.f;
#pragma unroll
      for (int ntl = 0; ntl < 3; ++ntl) {
        float evv = (float)Ew[fm * ESTR + ntl * 16 + rlo];
        n2s = fmaf(P[mtl][ntl][rr], evv, n2s);
      }
#pragma unroll
      for (int d = 1; d < 16; d <<= 1) n2s += __shfl_xor(n2s, d);
      float nm = __shfl(sn[mtl], hi * 4 + rr);
      float n1v = __shfl(n1lane, fm);
      float denom = n1v * sqrtf(fmaxf(n2s, 0.f));
      float sim = nm / fmaxf(denom, 1e-20f);
      ef += (fm < iL) ? __expf(LLSE * sim) : 0.f;
    }
  }
  ef += __shfl_xor(ef, 16);
  ef += __shfl_xor(ef, 32);
  if (lane == 0) S[(j << 6) + i] = __logf(ef) * (1.f / LLSE);
}

// ---------------- k_loss ----------------
__global__ void k_loss(const float* __restrict__ S, float* __restrict__ out) {
  __shared__ float red[128];
  int t = threadIdx.x;
  float m = -1e30f;
  if (t < 64) {
    int a = t;
    float da = S[a * N + a];
    for (int b = 0; b < N; ++b)
      if (b != a) m = fmaxf(m, MARG + S[a * N + b] - da);
  } else {
    int b = t - 64;
    float db = S[b * N + b];
    for (int a = 0; a < N; ++a)
      if (a != b) m = fmaxf(m, MARG + S[a * N + b] - db);
  }
  m = fmaxf(m, 0.f);
  red[t] = m;
  __syncthreads();
  if (t == 0) {
    float s = 0.f;
    for (int k = 0; k < 128; ++k) s += red[k];
    *out = s;
  }
}

extern "C" void kernel_launch(void* const* d_in, const int* in_sizes, int n_in,
                              void* d_out, int out_size, void* d_ws, size_t ws_size,
                              hipStream_t stream) {
  const float* img = (const float*)d_in[0];
  const float* cap = (const float*)d_in[1];
  const int* imgL = (const int*)d_in[2];
  const int* capL = (const int*)d_in[3];

  char* wsb = (char*)d_ws;
  float* n1 = (float*)wsb;                                // 16 KB
  float* S = (float*)(wsb + 16384);                       // 16 KB
  _Float16* img_h = (_Float16*)(wsb + 32768);             // 4 MB
  _Float16* cap_h = (_Float16*)(wsb + 32768 + 4194304);   // 3 MB
  _Float16* G_h = (_Float16*)(wsb + 32768 + 4194304 + 3145728);  // 384 KB

  k_pre<<<192, 512, 0, stream>>>(img, cap, img_h, cap_h, G_h, n1);
  k_main<<<512, 512, 0, stream>>>(img_h, cap_h, imgL, capL, n1, G_h, S);
  k_loss<<<1, 128, 0, stream>>>(S, (float*)d_out);
}

// Round 10
// 56.736 us; speedup vs baseline: 2.0104x; 1.0013x over previous
//
#include <hip/hip_runtime.h>
#include <math.h>

#define N 64
#define F 64
#define W 40
#define D 512
#define LSM 9.0f
#define LLSE 6.0f
#define MARG 0.2f
#define ESTR 56  // Es row stride in halves

typedef _Float16 f16x8 __attribute__((ext_vector_type(8)));
typedef _Float16 f16x4 __attribute__((ext_vector_type(4)));
typedef float f32x4 __attribute__((ext_vector_type(4)));

__device__ inline void gll16(const void* g, void* l) {
  __builtin_amdgcn_global_load_lds(
      (const __attribute__((address_space(1))) unsigned int*)g,
      (__attribute__((address_space(3))) unsigned int*)l, 16, 0, 0);
}

// layouts (halves), K-chunked (8 chunks of 64) + XOR swizzle baked in:
//  img_h per i: [ch8][f64][64],  halfidx ^ ((f&7)<<3)               (32768)
//  cap_h per j: [ch8][w48][64], halfidx ^ ((w&7)<<3), rows 40..47=0 (24576)
//  G_h  per j: [w48][64] linear, zero outside 40 rows/48 cols       (3072)

// ---------------- k_pre: grid 320 x 512 ----------------
// blocks [0,256): img convert fp16 swizzled-chunked + n1 (16 rows/block)
// blocks [256,320): cap convert + Gram via MFMA (8 waves)
__global__ __launch_bounds__(512) void k_pre(
    const float* __restrict__ img, const float* __restrict__ cap,
    _Float16* __restrict__ img_h, _Float16* __restrict__ cap_h,
    _Float16* __restrict__ G_h, float* __restrict__ n1) {
  __shared__ __align__(16) _Float16 capT[4 * 48 * 128];  // 48 KB (cap blocks only)
  int t = threadIdx.x;
  int b = blockIdx.x;
  if (b < 256) {
    int i = b >> 2;
    int f = ((b & 3) << 4) + (t >> 5);
    int q = t & 31;  // 16 halves per thread
    const float* row = img + ((size_t)i * F + f) * D + q * 16;
    _Float16* dsti = img_h + (size_t)i * 32768;
    int fsw = (f & 7) << 3;
    float s = 0.f;
    int d0 = q * 16;
    int ch = d0 >> 6, din = d0 & 63;  // 16-run never crosses a 64 boundary
#pragma unroll
    for (int k = 0; k < 2; ++k) {
      float4 u = *(const float4*)(row + k * 8);
      float4 v = *(const float4*)(row + k * 8 + 4);
      s += u.x * u.x + u.y * u.y + u.z * u.z + u.w * u.w;
      s += v.x * v.x + v.y * v.y + v.z * v.z + v.w * v.w;
      f16x8 h;
      h[0] = (_Float16)u.x; h[1] = (_Float16)u.y; h[2] = (_Float16)u.z; h[3] = (_Float16)u.w;
      h[4] = (_Float16)v.x; h[5] = (_Float16)v.y; h[6] = (_Float16)v.z; h[7] = (_Float16)v.w;
      *(f16x8*)(dsti + ch * 4096 + f * 64 + ((din + k * 8) ^ fsw)) = h;
    }
    s += __shfl_xor(s, 1);
    s += __shfl_xor(s, 2);
    s += __shfl_xor(s, 4);
    s += __shfl_xor(s, 8);
    s += __shfl_xor(s, 16);
    if (q == 0) n1[i * F + f] = sqrtf(s);
  } else {
    int j = b - 256;
    int lane = t & 63, wv = t >> 6;
    const float* src = cap + (size_t)j * W * D;
    _Float16* dst = cap_h + (size_t)j * 24576;
#pragma unroll
    for (int k = 0; k < 6; ++k) {
      int slot = t + k * 512;  // 48 rows x 64 col-chunks
      int w = slot >> 6, d = (slot & 63) * 8;
      float4 u = {0.f, 0.f, 0.f, 0.f}, v = {0.f, 0.f, 0.f, 0.f};
      if (w < W) {
        u = *(const float4*)(src + (size_t)w * D + d);
        v = *(const float4*)(src + (size_t)w * D + d + 4);
      }
      f16x8 h;
      h[0] = (_Float16)u.x; h[1] = (_Float16)u.y; h[2] = (_Float16)u.z; h[3] = (_Float16)u.w;
      h[4] = (_Float16)v.x; h[5] = (_Float16)v.y; h[6] = (_Float16)v.z; h[7] = (_Float16)v.w;
      int wsw = (w & 7) << 3;
      int ch2 = d >> 6, din2 = d & 63;
      *(f16x8*)(dst + ch2 * 3072 + w * 64 + (din2 ^ wsw)) = h;
      int chO = d >> 7, dinO = d & 127;
      *(f16x8*)(capT + chO * 6144 + w * 128 + (dinO ^ wsw)) = h;
    }
    __syncthreads();
    int rlo = lane & 15, hi = lane >> 4;
    int koff = hi * 8, sw = (rlo & 7) << 3;
    _Float16* gb = G_h + (size_t)j * 3072;
    for (int tile = wv; tile < 9; tile += 8) {
      int mt = tile / 3, kt = tile % 3;
      f32x4 acc = (f32x4)0.f;
#pragma unroll
      for (int ks = 0; ks < 16; ++ks) {
        int kk = ks * 32 + koff;
        int ch = kk >> 7, din = (kk & 127) ^ sw;
        f16x8 af = *(const f16x8*)(capT + ch * 6144 + (mt * 16 + rlo) * 128 + din);
        f16x8 bf = *(const f16x8*)(capT + ch * 6144 + (kt * 16 + rlo) * 128 + din);
        acc = __builtin_amdgcn_mfma_f32_16x16x32_f16(af, bf, acc, 0, 0, 0);
      }
#pragma unroll
      for (int r = 0; r < 4; ++r) {
        int w = mt * 16 + hi * 4 + r, k = kt * 16 + rlo;
        float val = (w < W && k < W) ? acc[r] : 0.f;
        gb[w * 64 + k] = (_Float16)val;
      }
    }
    // zero G cols 48..63 (K-tail read by k_main against E garbage -> must be 0)
    if (t < 96) {
      int w = t >> 1, c8 = 48 + (t & 1) * 8;
      *(f16x8*)(gb + w * 64 + c8) = (f16x8)(_Float16)0.f;
    }
  }
}

// ---------------- k_main: 512 blocks x 512 thr; block = 4j x 2i = 8 pairs ----------------
// 2D XCD tiling: each XCD owns 16 imgs x 32 caps = 2.7 MB (L2-resident).
// Counted-vmcnt pipeline (T3/T4); staging descriptors hoisted out of the chunk loop.
__global__ __launch_bounds__(512, 4) void k_main(
    const _Float16* __restrict__ img_h, const _Float16* __restrict__ cap_h,
    const int* __restrict__ imgL, const int* __restrict__ capL,
    const float* __restrict__ n1g, const _Float16* __restrict__ G_h,
    float* __restrict__ S) {
  __shared__ __align__(16) char buf[81920];  // 2 x 40KB chunk dbuf; Es aliased later

  int t = threadIdx.x;
  int lane = t & 63, wv = t >> 6;
  int rlo = lane & 15, hi = lane >> 4;
  int koff = hi * 8;
  int sw = (rlo & 7) << 3;

  int bid = blockIdx.x;
  int xcd = bid & 7, s0 = bid >> 3;
  int jloc = wv & 3, iloc = wv >> 2;
  // XCD owns: imgs [(xcd&3)*16, +16), caps [(xcd>>2)*32, +32)
  int i = (xcd & 3) * 16 + (s0 & 7) * 2 + iloc;
  int j = (xcd >> 2) * 32 + (s0 >> 3) * 4 + jloc;

  // issue BEFORE stage(0): these are the oldest vmcnt entries
  int iL = imgL[i], cL = capL[j];

  const char* capb = (const char*)cap_h + (size_t)(j - jloc) * 49152;
  const char* imgb = (const char*)img_h + (size_t)(i - iloc) * 65536;

  // hoisted staging descriptors (loop-invariant; s unrolled -> registers)
  const char* bsrc[5];
  int cstr[5], mdst[5];
#pragma unroll
  for (int s = 0; s < 5; ++s) {
    int m = s * 8 + wv;  // wave-uniform segment id, 40 x 1KB segments
    if (m < 24) {
      bsrc[s] = capb + (m / 6) * 49152 + (m % 6) * 1024 + lane * 16;
      cstr[s] = 6144;
    } else {
      int e = m - 24;
      bsrc[s] = imgb + (e >> 3) * 65536 + (e & 7) * 1024 + lane * 16;
      cstr[s] = 8192;
    }
    mdst[s] = m * 1024;
  }

  f32x4 acc[3][4];
#pragma unroll
  for (int mt = 0; mt < 3; ++mt)
#pragma unroll
    for (int nt = 0; nt < 4; ++nt) acc[mt][nt] = (f32x4)0.f;

  // prologue: stage chunk 0 (5 gll in flight)
#pragma unroll
  for (int s = 0; s < 5; ++s) gll16(bsrc[s], buf + mdst[s]);

  // ---- A-phase: counted-vmcnt two-barrier pipeline, 8 chunks ----
#pragma unroll
  for (int c = 0; c < 8; ++c) {
    if (c < 7) {
      char* db = buf + ((c + 1) & 1) * 40960;
#pragma unroll
      for (int s = 0; s < 5; ++s) gll16(bsrc[s] + (c + 1) * cstr[s], db + mdst[s]);
      asm volatile("s_waitcnt vmcnt(5)" ::: "memory");  // chunk-c landed; c+1 in flight
    } else {
      asm volatile("s_waitcnt vmcnt(0)" ::: "memory");
    }
    __builtin_amdgcn_s_barrier();
    __builtin_amdgcn_sched_barrier(0);
    const char* cb = buf + (c & 1) * 40960;
    const _Float16* myCap = (const _Float16*)cb + jloc * 3072;
    const _Float16* myImg = (const _Float16*)(cb + 24576) + iloc * 4096;
#pragma unroll
    for (int ks = 0; ks < 2; ++ks) {
      int col = (ks * 32 + koff) ^ sw;
      f16x8 af[3], bf[4];
#pragma unroll
      for (int mt = 0; mt < 3; ++mt) af[mt] = *(const f16x8*)(myCap + (mt * 16 + rlo) * 64 + col);
#pragma unroll
      for (int nt = 0; nt < 4; ++nt) bf[nt] = *(const f16x8*)(myImg + (nt * 16 + rlo) * 64 + col);
#pragma unroll
      for (int mt = 0; mt < 3; ++mt)
#pragma unroll
        for (int nt = 0; nt < 4; ++nt)
          acc[mt][nt] = __builtin_amdgcn_mfma_f32_16x16x32_f16(af[mt], bf[nt], acc[mt][nt], 0, 0, 0);
    }
    __builtin_amdgcn_sched_barrier(0);
    __builtin_amdgcn_s_barrier();  // all reads of buf[c&1] done -> c+2 may overwrite
  }

  // ---- epilogue: wave-private, zero barriers. Es aliases staging buffer ----
  _Float16* Ew = (_Float16*)(buf + wv * 7168);  // [64][ESTR=56] halves
  float n1lane = n1g[i * F + lane];

  // rnorm: rinv per w from sum_f leaky(A)^2 (f-masked)
  float rinv[3][4];
#pragma unroll
  for (int mt = 0; mt < 3; ++mt)
#pragma unroll
    for (int r = 0; r < 4; ++r) {
      float s = 0.f;
#pragma unroll
      for (int nt = 0; nt < 4; ++nt) {
        float a = acc[mt][nt][r];
        float l = a > 0.f ? a : 0.1f * a;
        s += ((nt * 16 + rlo) < iL) ? l * l : 0.f;
      }
#pragma unroll
      for (int d = 1; d < 16; d <<= 1) s += __shfl_xor(s, d);
      rinv[mt][r] = 1.f / (sqrtf(s) + 1e-8f);
    }

  // fused softmax (logits in [-9,9] -> no max pass) + sn + Es write
  float sn[4] = {0.f, 0.f, 0.f, 0.f};
#pragma unroll
  for (int mt = 0; mt < 3; ++mt)
#pragma unroll
    for (int nt = 0; nt < 4; ++nt) {
      f16x4 ev;
#pragma unroll
      for (int r = 0; r < 4; ++r) {
        int w = mt * 16 + hi * 4 + r;
        float a = acc[mt][nt][r];
        float l = a > 0.f ? a : 0.1f * a;
        float e = (w < cL) ? __expf(LSM * l * rinv[mt][r]) : 0.f;
        sn[nt] = fmaf(e, a, sn[nt]);
        ev[r] = (_Float16)e;
      }
      *(f16x4*)(Ew + (nt * 16 + rlo) * ESTR + mt * 16 + hi * 4) = ev;
    }
#pragma unroll
  for (int nt = 0; nt < 4; ++nt) {
    sn[nt] += __shfl_xor(sn[nt], 16);
    sn[nt] += __shfl_xor(sn[nt], 32);
  }

  // P = E*G (24 MFMA; E K-tail garbage cols >=48 killed by G zero-cols; G symmetric)
  const _Float16* gB = G_h + (size_t)j * 3072 + rlo * 64 + koff;
  f32x4 P[4][3];
#pragma unroll
  for (int mtl = 0; mtl < 4; ++mtl)
#pragma unroll
    for (int ntl = 0; ntl < 3; ++ntl) P[mtl][ntl] = (f32x4)0.f;
#pragma unroll
  for (int ks2 = 0; ks2 < 2; ++ks2) {
    int kk2 = ks2 * 32;
    f16x8 bfg[3];
#pragma unroll
    for (int ntl = 0; ntl < 3; ++ntl) bfg[ntl] = *(const f16x8*)(gB + ntl * 1024 + kk2);
#pragma unroll
    for (int mtl = 0; mtl < 4; ++mtl) {
      f16x8 af = *(const f16x8*)(Ew + (mtl * 16 + rlo) * ESTR + kk2 + koff);
#pragma unroll
      for (int ntl = 0; ntl < 3; ++ntl)
        P[mtl][ntl] = __builtin_amdgcn_mfma_f32_16x16x32_f16(af, bfg[ntl], P[mtl][ntl], 0, 0, 0);
    }
  }

  // n2^2 per f; sim; LSE over f; one store per wave
  float ef = 0.f;
#pragma unroll
  for (int mtl = 0; mtl < 4; ++mtl) {
#pragma unroll
    for (int rr = 0; rr < 4; ++rr) {
      int fm = mtl * 16 + hi * 4 + rr;
      float n2s = 0.f;
#pragma unroll
      for (int ntl = 0; ntl < 3; ++ntl) {
        float evv = (float)Ew[fm * ESTR + ntl * 16 + rlo];
        n2s = fmaf(P[mtl][ntl][rr], evv, n2s);
      }
#pragma unroll
      for (int d = 1; d < 16; d <<= 1) n2s += __shfl_xor(n2s, d);
      float nm = __shfl(sn[mtl], hi * 4 + rr);
      float n1v = __shfl(n1lane, fm);
      float denom = n1v * sqrtf(fmaxf(n2s, 0.f));
      float sim = nm / fmaxf(denom, 1e-20f);
      ef += (fm < iL) ? __expf(LLSE * sim) : 0.f;
    }
  }
  ef += __shfl_xor(ef, 16);
  ef += __shfl_xor(ef, 32);
  if (lane == 0) S[(j << 6) + i] = __logf(ef) * (1.f / LLSE);
}

// ---------------- k_loss ----------------
__global__ void k_loss(const float* __restrict__ S, float* __restrict__ out) {
  __shared__ float red[128];
  int t = threadIdx.x;
  float m = -1e30f;
  if (t < 64) {
    int a = t;
    float da = S[a * N + a];
    for (int b = 0; b < N; ++b)
      if (b != a) m = fmaxf(m, MARG + S[a * N + b] - da);
  } else {
    int b = t - 64;
    float db = S[b * N + b];
    for (int a = 0; a < N; ++a)
      if (a != b) m = fmaxf(m, MARG + S[a * N + b] - db);
  }
  red[t] = fmaxf(m, 0.f);
  __syncthreads();
  if (t < 64) {
    float v = red[t] + red[t + 64];
#pragma unroll
    for (int off = 1; off < 64; off <<= 1) v += __shfl_xor(v, off);
    if (t == 0) *out = v;
  }
}

extern "C" void kernel_launch(void* const* d_in, const int* in_sizes, int n_in,
                              void* d_out, int out_size, void* d_ws, size_t ws_size,
                              hipStream_t stream) {
  const float* img = (const float*)d_in[0];
  const float* cap = (const float*)d_in[1];
  const int* imgL = (const int*)d_in[2];
  const int* capL = (const int*)d_in[3];

  char* wsb = (char*)d_ws;
  float* n1 = (float*)wsb;                                // 16 KB
  float* S = (float*)(wsb + 16384);                       // 16 KB
  _Float16* img_h = (_Float16*)(wsb + 32768);             // 4 MB
  _Float16* cap_h = (_Float16*)(wsb + 32768 + 4194304);   // 3 MB
  _Float16* G_h = (_Float16*)(wsb + 32768 + 4194304 + 3145728);  // 384 KB

  k_pre<<<320, 512, 0, stream>>>(img, cap, img_h, cap_h, G_h, n1);
  k_main<<<512, 512, 0, stream>>>(img_h, cap_h, imgL, capL, n1, G_h, S);
  k_loss<<<1, 128, 0, stream>>>(S, (float*)d_out);
}